// Round 7
// baseline (851.994 us; speedup 1.0000x reference)
//
#include <hip/hip_runtime.h>
#include <hip/hip_bf16.h>

typedef __attribute__((ext_vector_type(8))) short short8;
typedef __attribute__((ext_vector_type(4))) int   int4v;
typedef __attribute__((ext_vector_type(4))) float f32x4;
typedef __attribute__((ext_vector_type(2))) float f32x2;

#define NN 100000
#define NE 3200000
#define NTILES (NE / 16)
#define NB 8192            // buckets (one per wave)
#define NBLK 256           // prep blocks
#define EPB (NE / NBLK)    // 12500 edges per prep block

__device__ __forceinline__ short f2bf(float f) {
  __hip_bfloat16 h = __float2bfloat16(f);
  return *reinterpret_cast<short*>(&h);
}
__device__ __forceinline__ f32x4 mfma16(short8 a, short8 b, f32x4 c) {
  return __builtin_amdgcn_mfma_f32_16x16x32_bf16(a, b, c, 0, 0, 0);
}
__device__ __forceinline__ int bucket_of(int d) {
  return (int)(((unsigned long long)d * NB) / NN);
}

// ---------------- prep: bucket-by-dst, no global atomics ----------------
__global__ void __launch_bounds__(256) k_count(const int* __restrict__ dst,
                                               int* __restrict__ cnt) {
  __shared__ int h[NB];
  for (int j = threadIdx.x; j < NB; j += 256) h[j] = 0;
  __syncthreads();
  const int e0 = blockIdx.x * EPB, e1 = e0 + EPB;
  for (int i = e0 + threadIdx.x; i < e1; i += 256)
    atomicAdd(&h[bucket_of(dst[i])], 1);
  __syncthreads();
  for (int j = threadIdx.x; j < NB; j += 256)
    cnt[blockIdx.x * NB + j] = h[j];
}

// per-bucket column scan over blocks (in-place: cnt becomes block offsets)
__global__ void __launch_bounds__(256) k_scan_cols(int* __restrict__ cnt,
                                                   int* __restrict__ total) {
  int b = blockIdx.x * 256 + threadIdx.x;
  if (b >= NB) return;
  int s = 0;
  for (int blk = 0; blk < NBLK; ++blk) {
    int idx = blk * NB + b;
    int t = cnt[idx];
    cnt[idx] = s;
    s += t;
  }
  total[b] = s;
}

// exclusive scan of total[NB] -> base[NB+1]
__global__ void __launch_bounds__(1024) k_scan_base(const int* __restrict__ total,
                                                    int* __restrict__ base) {
  __shared__ int sm[1024];
  const int tid = threadIdx.x;
  int t[8], pre[8], cs = 0;
#pragma unroll
  for (int k = 0; k < 8; ++k) { t[k] = total[tid * 8 + k]; pre[k] = cs; cs += t[k]; }
  sm[tid] = cs;
  __syncthreads();
  for (int off = 1; off < 1024; off <<= 1) {
    int x = (tid >= off) ? sm[tid - off] : 0;
    __syncthreads();
    sm[tid] += x;
    __syncthreads();
  }
  int excl = sm[tid] - cs;
#pragma unroll
  for (int k = 0; k < 8; ++k) base[tid * 8 + k] = excl + pre[k];
  if (tid == 1023) base[NB] = sm[1023];
}

// scatter into bucket-ordered records (LDS cursor, no global atomics)
__global__ void __launch_bounds__(256) k_scatter(const int* __restrict__ src,
                                                 const int* __restrict__ dst,
                                                 const int* __restrict__ bm,
                                                 const float* __restrict__ x_edge,
                                                 const int* __restrict__ cnt,
                                                 const int* __restrict__ base,
                                                 int4v* __restrict__ recA,
                                                 float* __restrict__ recXE) {
  __shared__ int cur[NB];
  for (int j = threadIdx.x; j < NB; j += 256)
    cur[j] = cnt[blockIdx.x * NB + j] + base[j];
  __syncthreads();
  const int e0 = blockIdx.x * EPB, e1 = e0 + EPB;
  for (int i = e0 + threadIdx.x; i < e1; i += 256) {
    int d = dst[i];
    int b = bucket_of(d);
    int p = atomicAdd(&cur[b], 1);
    int4v ra = { src[i] | (bm[i] << 30), d, i, 0 };
    recA[p] = ra;
    const f32x2* xs = (const f32x2*)(x_edge + (size_t)i * 6);
    f32x2* xd = (f32x2*)(recXE + (size_t)p * 6);
    xd[0] = xs[0]; xd[1] = xs[1]; xd[2] = xs[2];
  }
}

// ---------------- main: one wave per bucket, zero global atomics ----------------
__global__ void __launch_bounds__(256) mpn_bucket(
    const float* __restrict__ x_node,
    const int4v* __restrict__ recA,
    const float* __restrict__ recXE,
    const int*   __restrict__ base,
    const float* __restrict__ Wn1, const float* __restrict__ bn1,
    const float* __restrict__ Wn2, const float* __restrict__ bn2,
    const float* __restrict__ We1, const float* __restrict__ be1,
    const float* __restrict__ We2, const float* __restrict__ be2,
    float* __restrict__ out_nm,
    float* __restrict__ out_em)
{
  __shared__ short lds_h1[4][16][40];
  __shared__ float lds_emf[4][96];
  __shared__ short lds_h2[4][16][72];
  __shared__ float accum[4][13 * 32];

  const int tid  = threadIdx.x;
  const int wid  = tid >> 6;
  const int lane = tid & 63;
  const int col  = lane & 15;
  const int kg   = lane >> 4;

  for (int i = lane; i < 13 * 32; i += 64) accum[wid][i] = 0.f;

  auto ldb = [&](const float* W, int K, int N, int kc, int nt) {
    int n  = nt * 16 + col;
    int k0 = kc * 32 + kg * 8;
    short8 r;
#pragma unroll
    for (int j = 0; j < 8; ++j) {
      int k = k0 + j;
      float v = (k < K && n < N) ? W[k * N + n] : 0.f;
      r[j] = f2bf(v);
    }
    return r;
  };

  short8 B_e1[3][2], B_n1[2][4], B_n2[2][2], B_e2;
#pragma unroll
  for (int kc = 0; kc < 3; ++kc)
#pragma unroll
    for (int nt = 0; nt < 2; ++nt) B_e1[kc][nt] = ldb(We1, 70, 32, kc, nt);
  B_e2 = ldb(We2, 32, 6, 0, 0);
#pragma unroll
  for (int kc = 0; kc < 2; ++kc)
#pragma unroll
    for (int nt = 0; nt < 4; ++nt) B_n1[kc][nt] = ldb(Wn1, 38, 64, kc, nt);
#pragma unroll
  for (int kc = 0; kc < 2; ++kc)
#pragma unroll
    for (int nt = 0; nt < 2; ++nt) B_n2[kc][nt] = ldb(Wn2, 64, 32, kc, nt);

  float bias_e1[2], bias_n1[4], bias_n2[2], bias_e2;
  bias_e1[0] = be1[col];      bias_e1[1] = be1[16 + col];
  bias_e2    = (col < 6) ? be2[col] : 0.f;
#pragma unroll
  for (int nt = 0; nt < 4; ++nt) bias_n1[nt] = bn1[nt * 16 + col];
  bias_n2[0] = bn2[col];      bias_n2[1] = bn2[16 + col];

  const int w = blockIdx.x * 4 + wid;          // bucket id == wave id
  if (w >= NB) return;
  const int n0 = (int)(((long long)w * NN + NB - 1) / NB);
  const int n1 = (int)(((long long)(w + 1) * NN + NB - 1) / NB);
  const int win = n1 - n0;                     // <= 13
  const int s0 = base[w], s1 = base[w + 1];
  const int ntl = (s1 - s0 + 15) >> 4;

  for (int ti = 0; ti < ntl; ++ti) {
    const int tb  = s0 + ti * 16;
    const int rem = min(16, s1 - tb);
    const int rp  = (col < rem) ? (tb + col) : (s1 - 1);

    int4v ra = recA[rp];
    const int s    = ra.x & 0x3FFFFFFF;
    const bool back = (ra.x >> 30) & 1;
    const int d    = ra.y;
    const int eid  = ra.z;

    // per-lane gather in fragment layout (8 floats of the row per kg group)
    const float* ps = x_node + (long)s * 32 + kg * 8;
    const float* pd = x_node + (long)d * 32 + kg * 8;
    f32x4 s0v = *(const f32x4*)ps, s1v = *(const f32x4*)(ps + 4);
    f32x4 d0v = *(const f32x4*)pd, d1v = *(const f32x4*)(pd + 4);
    short8 XS, XD;
#pragma unroll
    for (int j = 0; j < 4; ++j) {
      XS[j] = f2bf(s0v[j]); XS[4 + j] = f2bf(s1v[j]);
      XD[j] = f2bf(d0v[j]); XD[4 + j] = f2bf(d1v[j]);
    }
    short8 AE = {0, 0, 0, 0, 0, 0, 0, 0};
    if (kg == 0) {
      const f32x2* pe = (const f32x2*)(recXE + (size_t)rp * 6);
      f32x2 e0 = pe[0], e1 = pe[1], e2 = pe[2];
      AE[0] = f2bf(e0[0]); AE[1] = f2bf(e0[1]);
      AE[2] = f2bf(e1[0]); AE[3] = f2bf(e1[1]);
      AE[4] = f2bf(e2[0]); AE[5] = f2bf(e2[1]);
    }
    short8 Aa = back ? XD : XS;
    short8 Ab = back ? XS : XD;

    // edge MLP layer 1
    f32x4 a0 = {bias_e1[0], bias_e1[0], bias_e1[0], bias_e1[0]};
    f32x4 a1 = {bias_e1[1], bias_e1[1], bias_e1[1], bias_e1[1]};
    a0 = mfma16(Aa, B_e1[0][0], a0);
    a0 = mfma16(Ab, B_e1[1][0], a0);
    a0 = mfma16(AE, B_e1[2][0], a0);
    a1 = mfma16(Aa, B_e1[0][1], a1);
    a1 = mfma16(Ab, B_e1[1][1], a1);
    a1 = mfma16(AE, B_e1[2][1], a1);

#pragma unroll
    for (int r = 0; r < 4; ++r) {
      lds_h1[wid][kg * 4 + r][col]      = f2bf(fmaxf(a0[r], 0.f));
      lds_h1[wid][kg * 4 + r][16 + col] = f2bf(fmaxf(a1[r], 0.f));
    }
    short8 Ah1 = *(const short8*)&lds_h1[wid][col][kg * 8];

    // edge MLP layer 2
    f32x4 ae2 = {bias_e2, bias_e2, bias_e2, bias_e2};
    ae2 = mfma16(Ah1, B_e2, ae2);

#pragma unroll
    for (int r = 0; r < 4; ++r) {
      int row = kg * 4 + r;
      if (col < 6) lds_emf[wid][row * 6 + col] = ae2[r];
    }
    // em scatter (masked rows skipped)
#pragma unroll
    for (int r = 0; r < 4; ++r) {
      int row = kg * 4 + r;
      int eidr = __shfl(eid, row);
      if (col < 6 && row < rem)
        out_em[(long)eidr * 6 + col] = ae2[r];
    }
    short8 Aem = {0, 0, 0, 0, 0, 0, 0, 0};
    if (kg == 0) {
      f32x2 u0 = *(const f32x2*)&lds_emf[wid][col * 6];
      f32x2 u1 = *(const f32x2*)&lds_emf[wid][col * 6 + 2];
      f32x2 u2 = *(const f32x2*)&lds_emf[wid][col * 6 + 4];
      Aem[0] = f2bf(u0[0]); Aem[1] = f2bf(u0[1]);
      Aem[2] = f2bf(u1[0]); Aem[3] = f2bf(u1[1]);
      Aem[4] = f2bf(u2[0]); Aem[5] = f2bf(u2[1]);
    }

    // node MLP layer 1
    f32x4 an[4];
#pragma unroll
    for (int nt = 0; nt < 4; ++nt) {
      an[nt] = (f32x4){bias_n1[nt], bias_n1[nt], bias_n1[nt], bias_n1[nt]};
      an[nt] = mfma16(XD,  B_n1[0][nt], an[nt]);
      an[nt] = mfma16(Aem, B_n1[1][nt], an[nt]);
    }
#pragma unroll
    for (int nt = 0; nt < 4; ++nt)
#pragma unroll
      for (int r = 0; r < 4; ++r)
        lds_h2[wid][kg * 4 + r][nt * 16 + col] = f2bf(fmaxf(an[nt][r], 0.f));
    short8 Ah2a = *(const short8*)&lds_h2[wid][col][kg * 8];
    short8 Ah2b = *(const short8*)&lds_h2[wid][col][32 + kg * 8];

    // node MLP layer 2
    f32x4 am0 = {bias_n2[0], bias_n2[0], bias_n2[0], bias_n2[0]};
    f32x4 am1 = {bias_n2[1], bias_n2[1], bias_n2[1], bias_n2[1]};
    am0 = mfma16(Ah2a, B_n2[0][0], am0);
    am0 = mfma16(Ah2b, B_n2[1][0], am0);
    am1 = mfma16(Ah2a, B_n2[0][1], am1);
    am1 = mfma16(Ah2b, B_n2[1][1], am1);

    // accumulate into per-wave LDS window (ds atomics only)
#pragma unroll
    for (int r = 0; r < 4; ++r) {
      int row = kg * 4 + r;
      if (row < rem) {
        int dloc = __shfl(d, row) - n0;
        atomicAdd(&accum[wid][dloc * 32 + col],      am0[r]);
        atomicAdd(&accum[wid][dloc * 32 + 16 + col], am1[r]);
      }
    }
  }

  // plain coalesced nm write (each node owned by exactly one wave)
  for (int rr = (lane >> 5); rr < win; rr += 2)
    out_nm[(long)(n0 + rr) * 32 + (lane & 31)] = accum[wid][rr * 32 + (lane & 31)];
}

// ---------------- legacy fallback (R6 kernel, atomics) ----------------
__global__ void __launch_bounds__(256) mpn_legacy(
    const float* __restrict__ x_node,
    const float* __restrict__ x_edge,
    const int*   __restrict__ srcp,
    const int*   __restrict__ dstp,
    const int*   __restrict__ bmp,
    const float* __restrict__ Wn1, const float* __restrict__ bn1,
    const float* __restrict__ Wn2, const float* __restrict__ bn2,
    const float* __restrict__ We1, const float* __restrict__ be1,
    const float* __restrict__ We2, const float* __restrict__ be2,
    float* __restrict__ out_nm,
    float* __restrict__ out_em)
{
  __shared__ short lds_h1[4][16][40];
  __shared__ float lds_emf[4][96];
  __shared__ short lds_h2[4][16][72];

  const int tid  = threadIdx.x;
  const int wid  = tid >> 6;
  const int lane = tid & 63;
  const int col  = lane & 15;
  const int kg   = lane >> 4;

  auto ldb = [&](const float* W, int K, int N, int kc, int nt) {
    int n  = nt * 16 + col;
    int k0 = kc * 32 + kg * 8;
    short8 r;
#pragma unroll
    for (int j = 0; j < 8; ++j) {
      int k = k0 + j;
      float v = (k < K && n < N) ? W[k * N + n] : 0.f;
      r[j] = f2bf(v);
    }
    return r;
  };

  short8 B_e1[3][2], B_n1[2][4], B_n2[2][2], B_e2;
#pragma unroll
  for (int kc = 0; kc < 3; ++kc)
#pragma unroll
    for (int nt = 0; nt < 2; ++nt) B_e1[kc][nt] = ldb(We1, 70, 32, kc, nt);
  B_e2 = ldb(We2, 32, 6, 0, 0);
#pragma unroll
  for (int kc = 0; kc < 2; ++kc)
#pragma unroll
    for (int nt = 0; nt < 4; ++nt) B_n1[kc][nt] = ldb(Wn1, 38, 64, kc, nt);
#pragma unroll
  for (int kc = 0; kc < 2; ++kc)
#pragma unroll
    for (int nt = 0; nt < 2; ++nt) B_n2[kc][nt] = ldb(Wn2, 64, 32, kc, nt);

  float bias_e1[2], bias_n1[4], bias_n2[2], bias_e2;
  bias_e1[0] = be1[col];      bias_e1[1] = be1[16 + col];
  bias_e2    = (col < 6) ? be2[col] : 0.f;
#pragma unroll
  for (int nt = 0; nt < 4; ++nt) bias_n1[nt] = bn1[nt * 16 + col];
  bias_n2[0] = bn2[col];      bias_n2[1] = bn2[16 + col];

  const int gw = blockIdx.x * 4 + wid;
  const int nw = gridDim.x * 4;

  for (int t = gw; t < NTILES; t += nw) {
    const int eb = t * 16;
    const int e  = eb + col;
    const int s  = srcp[e];
    const int d  = dstp[e];
    const bool back = bmp[e] != 0;

    const float* ps = x_node + (long)s * 32 + kg * 8;
    const float* pd = x_node + (long)d * 32 + kg * 8;
    f32x4 s0 = *(const f32x4*)ps, s1 = *(const f32x4*)(ps + 4);
    f32x4 d0 = *(const f32x4*)pd, d1 = *(const f32x4*)(pd + 4);
    short8 XS, XD;
#pragma unroll
    for (int j = 0; j < 4; ++j) {
      XS[j] = f2bf(s0[j]); XS[4 + j] = f2bf(s1[j]);
      XD[j] = f2bf(d0[j]); XD[4 + j] = f2bf(d1[j]);
    }
    short8 AE = {0, 0, 0, 0, 0, 0, 0, 0};
    if (kg == 0) {
      const float* pe = x_edge + (long)e * 6;
      f32x2 e0 = *(const f32x2*)pe;
      f32x2 e1 = *(const f32x2*)(pe + 2);
      f32x2 e2 = *(const f32x2*)(pe + 4);
      AE[0] = f2bf(e0[0]); AE[1] = f2bf(e0[1]);
      AE[2] = f2bf(e1[0]); AE[3] = f2bf(e1[1]);
      AE[4] = f2bf(e2[0]); AE[5] = f2bf(e2[1]);
    }
    short8 Aa = back ? XD : XS;
    short8 Ab = back ? XS : XD;

    f32x4 a0 = {bias_e1[0], bias_e1[0], bias_e1[0], bias_e1[0]};
    f32x4 a1 = {bias_e1[1], bias_e1[1], bias_e1[1], bias_e1[1]};
    a0 = mfma16(Aa, B_e1[0][0], a0);
    a0 = mfma16(Ab, B_e1[1][0], a0);
    a0 = mfma16(AE, B_e1[2][0], a0);
    a1 = mfma16(Aa, B_e1[0][1], a1);
    a1 = mfma16(Ab, B_e1[1][1], a1);
    a1 = mfma16(AE, B_e1[2][1], a1);

#pragma unroll
    for (int r = 0; r < 4; ++r) {
      lds_h1[wid][kg * 4 + r][col]      = f2bf(fmaxf(a0[r], 0.f));
      lds_h1[wid][kg * 4 + r][16 + col] = f2bf(fmaxf(a1[r], 0.f));
    }
    short8 Ah1 = *(const short8*)&lds_h1[wid][col][kg * 8];

    f32x4 ae2 = {bias_e2, bias_e2, bias_e2, bias_e2};
    ae2 = mfma16(Ah1, B_e2, ae2);

    if (col < 6) {
#pragma unroll
      for (int r = 0; r < 4; ++r) {
        int row = kg * 4 + r;
        float v = ae2[r];
        out_em[(long)(eb + row) * 6 + col] = v;
        lds_emf[wid][row * 6 + col] = v;
      }
    }
    short8 Aem = {0, 0, 0, 0, 0, 0, 0, 0};
    if (kg == 0) {
      f32x2 u0 = *(const f32x2*)&lds_emf[wid][col * 6];
      f32x2 u1 = *(const f32x2*)&lds_emf[wid][col * 6 + 2];
      f32x2 u2 = *(const f32x2*)&lds_emf[wid][col * 6 + 4];
      Aem[0] = f2bf(u0[0]); Aem[1] = f2bf(u0[1]);
      Aem[2] = f2bf(u1[0]); Aem[3] = f2bf(u1[1]);
      Aem[4] = f2bf(u2[0]); Aem[5] = f2bf(u2[1]);
    }

    f32x4 an[4];
#pragma unroll
    for (int nt = 0; nt < 4; ++nt) {
      an[nt] = (f32x4){bias_n1[nt], bias_n1[nt], bias_n1[nt], bias_n1[nt]};
      an[nt] = mfma16(XD,  B_n1[0][nt], an[nt]);
      an[nt] = mfma16(Aem, B_n1[1][nt], an[nt]);
    }
#pragma unroll
    for (int nt = 0; nt < 4; ++nt)
#pragma unroll
      for (int r = 0; r < 4; ++r)
        lds_h2[wid][kg * 4 + r][nt * 16 + col] = f2bf(fmaxf(an[nt][r], 0.f));
    short8 Ah2a = *(const short8*)&lds_h2[wid][col][kg * 8];
    short8 Ah2b = *(const short8*)&lds_h2[wid][col][32 + kg * 8];

    f32x4 am0 = {bias_n2[0], bias_n2[0], bias_n2[0], bias_n2[0]};
    f32x4 am1 = {bias_n2[1], bias_n2[1], bias_n2[1], bias_n2[1]};
    am0 = mfma16(Ah2a, B_n2[0][0], am0);
    am0 = mfma16(Ah2b, B_n2[1][0], am0);
    am1 = mfma16(Ah2a, B_n2[0][1], am1);
    am1 = mfma16(Ah2b, B_n2[1][1], am1);

#pragma unroll
    for (int r = 0; r < 4; ++r) {
      int de = __shfl(d, kg * 4 + r);
      float* basep = out_nm + (long)de * 32 + col;
      unsafeAtomicAdd(basep,      am0[r]);
      unsafeAtomicAdd(basep + 16, am1[r]);
    }
  }
}

extern "C" void kernel_launch(void* const* d_in, const int* in_sizes, int n_in,
                              void* d_out, int out_size, void* d_ws, size_t ws_size,
                              hipStream_t stream) {
  const float* x_node = (const float*)d_in[0];
  const float* x_edge = (const float*)d_in[1];
  const int*   src    = (const int*)d_in[2];
  const int*   dst    = (const int*)d_in[3];
  const int*   bm     = (const int*)d_in[4];
  const float* Wn1 = (const float*)d_in[5];  const float* bn1 = (const float*)d_in[6];
  const float* Wn2 = (const float*)d_in[7];  const float* bn2 = (const float*)d_in[8];
  const float* We1 = (const float*)d_in[9];  const float* be1 = (const float*)d_in[10];
  const float* We2 = (const float*)d_in[11]; const float* be2 = (const float*)d_in[12];
  float* out_nm = (float*)d_out;
  float* out_em = out_nm + (size_t)NN * 32;

  // ws carve-up (16B-aligned offsets)
  const size_t o_cnt   = 0;                                   // 256*8192*4 = 8,388,608
  const size_t o_total = o_cnt + (size_t)NBLK * NB * 4;       // 32,768
  const size_t o_base  = o_total + (size_t)NB * 4;            // (NB+1)*4 -> pad 32,784
  const size_t o_recA  = o_base + 32784;                      // NE*16
  const size_t o_recXE = o_recA + (size_t)NE * 16;            // NE*24
  const size_t need    = o_recXE + (size_t)NE * 24;           // ~136.5 MB

  if (ws_size >= need) {
    char* w = (char*)d_ws;
    int*   cnt   = (int*)(w + o_cnt);
    int*   total = (int*)(w + o_total);
    int*   base  = (int*)(w + o_base);
    int4v* recA  = (int4v*)(w + o_recA);
    float* recXE = (float*)(w + o_recXE);

    k_count<<<NBLK, 256, 0, stream>>>(dst, cnt);
    k_scan_cols<<<NB / 256, 256, 0, stream>>>(cnt, total);
    k_scan_base<<<1, 1024, 0, stream>>>(total, base);
    k_scatter<<<NBLK, 256, 0, stream>>>(src, dst, bm, x_edge, cnt, base, recA, recXE);
    mpn_bucket<<<NB / 4, 256, 0, stream>>>(x_node, recA, recXE, base,
                                           Wn1, bn1, Wn2, bn2, We1, be1, We2, be2,
                                           out_nm, out_em);
  } else {
    hipMemsetAsync(out_nm, 0, (size_t)NN * 32 * sizeof(float), stream);
    mpn_legacy<<<2048, 256, 0, stream>>>(x_node, x_edge, src, dst, bm,
                                         Wn1, bn1, Wn2, bn2, We1, be1, We2, be2,
                                         out_nm, out_em);
  }
}